// Round 12
// baseline (207.028 us; speedup 1.0000x reference)
//
#include <hip/hip_runtime.h>
#include <math.h>

// Problem constants (reference: B=4, S=2048, E=384, H=8, D=48)
#define B_ 4
#define S_ 2048
#define E_ 384
#define H_ 8
#define D_ 48
#define M_ (B_*S_)            // 8192 rows
#define DP_ 64                // padded head dim in Qp/Kp
constexpr float QK_SCALE = 0.14433756729740643f * 1.4426950408889634f; // 1/sqrt(48) * log2(e)

typedef __attribute__((ext_vector_type(8))) short short8;   // 8 bf16 = 4 VGPRs
typedef __attribute__((ext_vector_type(4))) float f32x4;
typedef unsigned short u16;

__device__ inline u16 f2bf(float f) {            // RNE fp32->bf16
    unsigned u = __float_as_uint(f);
    return (u16)((u + 0x7FFFu + ((u >> 16) & 1u)) >> 16);
}
__device__ inline float bf2f(u16 h) { return __uint_as_float(((unsigned)h) << 16); }
__device__ inline unsigned pk2(float a, float b) {
    return (unsigned)f2bf(a) | ((unsigned)f2bf(b) << 16);
}
// round-half-up packed fp32x2 -> bf16x2 (1 perm + 2 adds)
__device__ inline unsigned pk2_fast(float a, float b) {
#if __has_builtin(__builtin_amdgcn_perm)
    unsigned ua = __float_as_uint(a) + 0x8000u;
    unsigned ub = __float_as_uint(b) + 0x8000u;
    return __builtin_amdgcn_perm(ub, ua, 0x07060302u);
#else
    return pk2(a, b);
#endif
}
__device__ inline float fexp2(float x) {
#if __has_builtin(__builtin_amdgcn_exp2f)
    return __builtin_amdgcn_exp2f(x);
#else
    return exp2f(x);
#endif
}
__device__ inline void glld16(const void* g, void* l) {
    __builtin_amdgcn_global_load_lds((const __attribute__((address_space(1))) unsigned int*)g,
                                     (__attribute__((address_space(3))) unsigned int*)l, 16, 0, 0);
}

// ---------------------------------------------------------------------------
// Fused prep: x->bf16 | weights->bf16 | Q/K pad columns.
// grid = 3072 (x) + 144 (w) + 256 (pad) = 3472 blocks.
// ---------------------------------------------------------------------------
__global__ __launch_bounds__(256) void prep(const float4* __restrict__ x,
                                            const int* __restrict__ mask,
                                            const float4* __restrict__ wq,
                                            const float4* __restrict__ wk,
                                            const float4* __restrict__ wv,
                                            const float4* __restrict__ wo,
                                            uint2* __restrict__ xb,
                                            uint2* __restrict__ wb,
                                            u16* __restrict__ Qp, u16* __restrict__ Kp) {
    const int bx = blockIdx.x, t = threadIdx.x;
    if (bx < 3072) {                               // x: NELEM/4 = 786432
        int i = bx * 256 + t;
        float4 v = x[i];
        uint2 H;
        H.x = pk2(v.x, v.y);
        H.y = pk2(v.z, v.w);
        xb[i] = H;
    } else if (bx < 3072 + 144) {                  // weights: WELEM/4 = 36864 each
        int i = (bx - 3072) * 256 + t;
        const int n4 = 36864;
        const float4* srcs[4] = {wq, wk, wv, wo};
        #pragma unroll
        for (int j = 0; j < 4; ++j) {
            float4 v = srcs[j][i];
            uint2 H;
            H.x = pk2(v.x, v.y);
            H.y = pk2(v.z, v.w);
            wb[(size_t)j * n4 + i] = H;
        }
    } else {                                       // pad cols 48..63 of Qp/Kp
        int i = (bx - 3216) * 256 + t;             // over BH*S = 65536
        int bh = i >> 11, s = i & 2047, b = bh >> 3;
        size_t off = ((size_t)bh * S_ + s) * DP_ + 48;
        uint4 qz = {0x00004300u, 0, 0, 0};         // col48 = 128.0, rest 0
        uint4 kz = {mask[b * S_ + s] ? 0x0000BF80u : 0u, 0, 0, 0}; // col48 = -1/0
        uint4 z  = {0, 0, 0, 0};
        *reinterpret_cast<uint4*>(Qp + off)     = qz;
        *reinterpret_cast<uint4*>(Qp + off + 8) = z;
        *reinterpret_cast<uint4*>(Kp + off)     = kz;
        *reinterpret_cast<uint4*>(Kp + off + 8) = z;
    }
}

// ---------------------------------------------------------------------------
// FUSED QKV GEMM: one 64m x 64n tile for ALL THREE weights (x staged once).
// grid (M/64, 6). LDS 32 KB single-buffered.
// Epilogues: V -> [bh][d][s] direct; Q/K -> LDS transpose -> [bh][s][64].
// ---------------------------------------------------------------------------
__global__ __launch_bounds__(256) void gemm_qkv3(const u16* __restrict__ xb,
                                                 const u16* __restrict__ wb,
                                                 const float* __restrict__ bq,
                                                 const float* __restrict__ bk,
                                                 const float* __restrict__ bv,
                                                 u16* __restrict__ Qp, u16* __restrict__ Kp,
                                                 u16* __restrict__ Vtp) {
    __shared__ u16 smem[4 * 4096];                 // As | WsQ | WsK | WsV (32 KB)
    u16* As = smem;

    const int t = threadIdx.x, w = t >> 6, lane = t & 63;
    const int ln = lane & 15, quad = lane >> 4;
    const int gr = lane >> 3;
    const int gc = (lane & 7) ^ gr;
    const int m0 = blockIdx.x * 64;
    const int n0 = blockIdx.y * 64;
    const int b  = m0 >> 11;                       // 64-row block never straddles batch

    f32x4 acc[3][4];
    #pragma unroll
    for (int j = 0; j < 3; ++j)
        #pragma unroll
        for (int nt = 0; nt < 4; ++nt)
            acc[j][nt] = (f32x4){0.f, 0.f, 0.f, 0.f};

    for (int kk = 0; kk < 384; kk += 64) {
        __syncthreads();                           // prior frag reads done
        #pragma unroll
        for (int i = 0; i < 2; ++i) {              // A: wave stages rows w*16..+16
            int r0 = w * 16 + i * 8;
            glld16(xb + (size_t)(m0 + r0 + gr) * E_ + kk + gc * 8, As + r0 * 64);
        }
        #pragma unroll
        for (int j = 0; j < 3; ++j)                // W_q, W_k, W_v tiles
            #pragma unroll
            for (int i = 0; i < 2; ++i) {
                int r0 = w * 16 + i * 8;
                glld16(wb + (size_t)j * 147456 + (size_t)(n0 + r0 + gr) * E_ + kk + gc * 8,
                       smem + (1 + j) * 4096 + r0 * 64);
            }
        __syncthreads();                           // staging visible

        #pragma unroll
        for (int ks = 0; ks < 2; ++ks) {
            const int slot = (ks * 4 + quad) ^ (ln & 7);
            short8 ah = *reinterpret_cast<const short8*>(&As[(w * 16 + ln) * 64 + slot * 8]);
            #pragma unroll
            for (int j = 0; j < 3; ++j) {
                const u16* Wsj = smem + (1 + j) * 4096;
                #pragma unroll
                for (int nt = 0; nt < 4; ++nt) {
                    short8 wf = *reinterpret_cast<const short8*>(&Wsj[(nt * 16 + ln) * 64 + slot * 8]);
                    acc[j][nt] = __builtin_amdgcn_mfma_f32_16x16x32_bf16(ah, wf, acc[j][nt], 0, 0, 0);
                }
            }
        }
    }

    // ---- V epilogue: [bh][d][s], 4 s-consecutive packed per 8B store ----
    {
        const int s_base = (m0 & 2047) + w * 16 + quad * 4;
        #pragma unroll
        for (int nt = 0; nt < 4; ++nt) {
            const int col = n0 + nt * 16 + ln;
            const int h   = (col * 683) >> 15;     // col / 48
            const int d   = col - h * 48;
            const float bc = bv[col];
            u16* dst = Vtp + ((size_t)(b * 8 + h) * 48 + d) * 2048;
            uint2 pk;
            pk.x = pk2(acc[2][nt][0] + bc, acc[2][nt][1] + bc);
            pk.y = pk2(acc[2][nt][2] + bc, acc[2][nt][3] + bc);
            *reinterpret_cast<uint2*>(dst + s_base) = pk;
        }
    }

    // ---- Q/K epilogue: transpose both through LDS, coalesced 16B stores ----
    u16* TrQ = smem;                               // [64][76] = 9728 B
    u16* TrK = smem + 64 * 76;                     // [64][76] (total 19456 B < 32 KB)
    __syncthreads();                               // frag reads done before overwrite
    #pragma unroll
    for (int nt = 0; nt < 4; ++nt) {
        const int col = n0 + nt * 16 + ln;
        const float bcq = bq[col], bck = bk[col];
        #pragma unroll
        for (int r = 0; r < 4; ++r) {
            int row = w * 16 + quad * 4 + r;
            TrQ[row * 76 + nt * 16 + ln] = f2bf((acc[0][nt][r] + bcq) * QK_SCALE);
            TrK[row * 76 + nt * 16 + ln] = f2bf(acc[1][nt][r] + bck);
        }
    }
    __syncthreads();
    {
        const int row = t >> 2, quarter = t & 3;
        const int s   = (m0 & 2047) + row;
        #pragma unroll
        for (int c = 0; c < 2; ++c) {
            int gcol = n0 + quarter * 16 + c * 8;  // 8-col chunk never straddles a head
            int h = (gcol * 683) >> 15;
            int d = gcol - h * 48;
            size_t off = ((size_t)(b * 8 + h) * 2048 + s) * DP_ + d;
            *reinterpret_cast<uint4*>(Qp + off) =
                *reinterpret_cast<const uint4*>(&TrQ[row * 76 + quarter * 16 + c * 8]);
            *reinterpret_cast<uint4*>(Kp + off) =
                *reinterpret_cast<const uint4*>(&TrK[row * 76 + quarter * 16 + c * 8]);
        }
    }
}

// ---------------------------------------------------------------------------
// O-proj: 64-row tiles, double-buffered, fp32 out.
// ---------------------------------------------------------------------------
__global__ __launch_bounds__(256) void gemm_out(const u16* __restrict__ ab,
                                                const u16* __restrict__ wb,
                                                const float* __restrict__ bo, float* __restrict__ out) {
    __shared__ u16 smem[2 * 4096 + 2 * 4096];          // 32 KB
    u16* As = smem;
    u16* Ws = smem + 2 * 4096;
    const int t = threadIdx.x, w = t >> 6, lane = t & 63;
    const int ln = lane & 15, quad = lane >> 4;
    const int gr = lane >> 3;
    const int gc = (lane & 7) ^ gr;
    const int m0 = blockIdx.x * 64, n0 = blockIdx.y * 64;
    const u16* wh = wb + (size_t)3 * 147456;

    f32x4 acc[4];
    #pragma unroll
    for (int nt = 0; nt < 4; ++nt) acc[nt] = (f32x4){0.f, 0.f, 0.f, 0.f};

    auto stage = [&](int bf, int kk) {
        #pragma unroll
        for (int i = 0; i < 2; ++i) {
            int r0 = w * 16 + i * 8;
            glld16(ab + (size_t)(m0 + r0 + gr) * E_ + kk + gc * 8, As + bf * 4096 + r0 * 64);
            glld16(wh + (size_t)(n0 + r0 + gr) * E_ + kk + gc * 8, Ws + bf * 4096 + r0 * 64);
        }
    };

    stage(0, 0);
    __syncthreads();
    #pragma unroll
    for (int it = 0; it < 6; ++it) {
        const int cur = it & 1;
        if (it < 5) stage(cur ^ 1, (it + 1) * 64);
        const u16* Ab = As + cur * 4096;
        const u16* Wb = Ws + cur * 4096;
        #pragma unroll
        for (int ks = 0; ks < 2; ++ks) {
            const int slot = (ks * 4 + quad) ^ (ln & 7);
            short8 ah = *reinterpret_cast<const short8*>(&Ab[(w * 16 + ln) * 64 + slot * 8]);
            #pragma unroll
            for (int nt = 0; nt < 4; ++nt) {
                short8 wf = *reinterpret_cast<const short8*>(&Wb[(nt * 16 + ln) * 64 + slot * 8]);
                acc[nt] = __builtin_amdgcn_mfma_f32_16x16x32_bf16(ah, wf, acc[nt], 0, 0, 0);
            }
        }
        __syncthreads();
    }

    #pragma unroll
    for (int nt = 0; nt < 4; ++nt) {
        const int col = n0 + nt * 16 + ln;
        const float bc = bo[col];
        #pragma unroll
        for (int r = 0; r < 4; ++r) {
            size_t row = (size_t)(m0 + w * 16 + quad * 4 + r);
            out[row * E_ + col] = acc[nt][r] + bc;
        }
    }
}

// ---------------------------------------------------------------------------
// BARRIER-FREE MFMA flash attention. Static softmax (associative) means no
// cross-wave dependency: K/V fragments load straight from global to VGPRs
// (16B contiguous per lane), no LDS staging, no __syncthreads in the loop.
// LDS only for the wave-private P round-trip (verified R11 swizzle).
// Grid (bh, q-tile): id%8 = bh%8 keeps K/V L2-resident per XCD.
// ---------------------------------------------------------------------------
__global__ __launch_bounds__(256, 2) void attn_mfma(const u16* __restrict__ Qp,
                                                    const u16* __restrict__ Kp,
                                                    const u16* __restrict__ Vtp,
                                                    u16* __restrict__ AO) {
    __shared__ __align__(16) u16 Ps[128 * 64];      // P only (wave-private rows)
    __shared__ float linv[4][32];

    const int t    = threadIdx.x;
    const int w    = t >> 6;
    const int lane = t & 63;
    const int ln   = lane & 15;
    const int quad = lane >> 4;
    const int bh   = blockIdx.x;                    // XCD-locality: id%8 = bh%8
    const int q0   = blockIdx.y * 128;
    const int b    = bh >> 3, h = bh & 7;
    const int cb   = h * 48;
    const size_t rb = (size_t)b * S_;

    const u16* Qsrc = Qp  + ((size_t)bh * S_ + q0 + w * 32) * DP_;
    const u16* Ksrc = Kp  + (size_t)bh * S_ * DP_;
    const u16* Vsrc = Vtp + (size_t)bh * 48 * 2048;

    // ---- P LDS addresses (R11-verified swizzle, wave-private rows) ----
    const int swz0 = ((quad    ) ^ (ln & 7)) << 3;
    const int swz1 = ((4 + quad) ^ (ln & 7)) << 3;
    const u16 *pR[2][2];
    u16* pW[2][4];
    #pragma unroll
    for (int qt = 0; qt < 2; ++qt) {
        const int qrow = (w * 32 + qt * 16 + ln) * 64;
        pR[qt][0] = &Ps[qrow + swz0];
        pR[qt][1] = &Ps[qrow + swz1];
        #pragma unroll
        for (int Mt = 0; Mt < 4; ++Mt)
            pW[qt][Mt] = &Ps[qrow +
                ((((Mt * 2 + (quad >> 1)) ^ (ln & 7)) << 3) | ((quad & 1) << 2))];
    }

    // ---- Q B-fragments straight from global (loop-invariant) ----
    // B[k=d][n=q]: lane needs Q[q=qt*16+ln][d=ks*32+quad*8 .. +7]
    short8 qf[2][2];
    #pragma unroll
    for (int qt = 0; qt < 2; ++qt)
        #pragma unroll
        for (int ks = 0; ks < 2; ++ks)
            qf[qt][ks] = *reinterpret_cast<const short8*>(
                Qsrc + (size_t)(qt * 16 + ln) * DP_ + ks * 32 + quad * 8);

    f32x4 o[2][3];
    #pragma unroll
    for (int qt = 0; qt < 2; ++qt)
        #pragma unroll
        for (int nt = 0; nt < 3; ++nt) o[qt][nt] = (f32x4){0.f, 0.f, 0.f, 0.f};
    float lq[2] = {0.f, 0.f};

    for (int kt = 0; kt < 32; ++kt) {
        const int k0 = kt * 64;

        // ---- K A-frags + V B-frags from global (16B contiguous per lane) ----
        // K: A[m=key=Mt*16+ln][k=d=ks*32+quad*8+j]
        short8 kf[4][2];
        #pragma unroll
        for (int Mt = 0; Mt < 4; ++Mt)
            #pragma unroll
            for (int ks = 0; ks < 2; ++ks)
                kf[Mt][ks] = *reinterpret_cast<const short8*>(
                    Ksrc + (size_t)(k0 + Mt * 16 + ln) * DP_ + ks * 32 + quad * 8);
        // V: B[k=key=ks*32+quad*8+j][n=d=nt*16+ln] from V^T[d][s]
        short8 vb[3][2];
        #pragma unroll
        for (int nt = 0; nt < 3; ++nt)
            #pragma unroll
            for (int ks = 0; ks < 2; ++ks)
                vb[nt][ks] = *reinterpret_cast<const short8*>(
                    Vsrc + (size_t)(nt * 16 + ln) * 2048 + k0 + ks * 32 + quad * 8);

        // ---- S^T = K·Q^T (mask folded in via pad col 48) ----
        f32x4 sc[4][2];
        #pragma unroll
        for (int Mt = 0; Mt < 4; ++Mt)
            #pragma unroll
            for (int qt = 0; qt < 2; ++qt) {
                f32x4 a0 = __builtin_amdgcn_mfma_f32_16x16x32_bf16(kf[Mt][0], qf[qt][0], (f32x4){0.f,0.f,0.f,0.f}, 0, 0, 0);
                sc[Mt][qt] = __builtin_amdgcn_mfma_f32_16x16x32_bf16(kf[Mt][1], qf[qt][1], a0, 0, 0, 0);
            }

        // ---- p = exp2(s); per-lane l; pack P (wave-private, no barrier) ----
        #pragma unroll
        for (int qt = 0; qt < 2; ++qt)
            #pragma unroll
            for (int Mt = 0; Mt < 4; ++Mt) {
                float p0 = fexp2(sc[Mt][qt][0]);
                float p1 = fexp2(sc[Mt][qt][1]);
                float p2 = fexp2(sc[Mt][qt][2]);
                float p3 = fexp2(sc[Mt][qt][3]);
                lq[qt] += (p0 + p1) + (p2 + p3);
                uint2 pk;
                pk.x = pk2_fast(p0, p1);
                pk.y = pk2_fast(p2, p3);
                *reinterpret_cast<uint2*>(pW[qt][Mt]) = pk;
            }

        // ---- PV (P read back within same wave; lgkmcnt only) ----
        short8 pa[2][2];
        #pragma unroll
        for (int qt = 0; qt < 2; ++qt) {
            pa[qt][0] = *reinterpret_cast<const short8*>(pR[qt][0]);
            pa[qt][1] = *reinterpret_cast<const short8*>(pR[qt][1]);
        }
        #pragma unroll
        for (int nt = 0; nt < 3; ++nt)
            #pragma unroll
            for (int qt = 0; qt < 2; ++qt) {
                o[qt][nt] = __builtin_amdgcn_mfma_f32_16x16x32_bf16(pa[qt][0], vb[nt][0], o[qt][nt], 0, 0, 0);
                o[qt][nt] = __builtin_amdgcn_mfma_f32_16x16x32_bf16(pa[qt][1], vb[nt][1], o[qt][nt], 0, 0, 0);
            }
    }

    // ---- epilogue: reduce l across quads (in-wave), divide, store bf16 AO ----
    #pragma unroll
    for (int qt = 0; qt < 2; ++qt) {
        float l = lq[qt];
        l += __shfl_xor(l, 16);
        l += __shfl_xor(l, 32);
        if (quad == 0) linv[w][qt * 16 + ln] = 1.0f / l;
    }
    __syncthreads();                                 // once per kernel; harmless
    #pragma unroll
    for (int qt = 0; qt < 2; ++qt) {
        f32x4 il = *reinterpret_cast<const f32x4*>(&linv[w][qt * 16 + quad * 4]);
        #pragma unroll
        for (int nt = 0; nt < 3; ++nt)
            #pragma unroll
            for (int r = 0; r < 4; ++r) {
                size_t row = rb + q0 + w * 32 + qt * 16 + quad * 4 + r;
                size_t idx = row * E_ + cb + nt * 16 + ln;
                AO[idx] = f2bf(o[qt][nt][r] * il[r]);
            }
    }
}

// ---------------------------------------------------------------------------
extern "C" void kernel_launch(void* const* d_in, const int* in_sizes, int n_in,
                              void* d_out, int out_size, void* d_ws, size_t ws_size,
                              hipStream_t stream) {
    (void)in_sizes; (void)n_in; (void)out_size; (void)ws_size;
    const float* x    = (const float*)d_in[0];
    const int*   mask = (const int*)  d_in[1];
    const float* Wq   = (const float*)d_in[2];
    const float* bq   = (const float*)d_in[3];
    const float* Wk   = (const float*)d_in[4];
    const float* bk   = (const float*)d_in[5];
    const float* Wv   = (const float*)d_in[6];
    const float* bv   = (const float*)d_in[7];
    const float* Wo   = (const float*)d_in[8];
    const float* bo   = (const float*)d_in[9];

    const size_t NELEM = (size_t)M_ * E_;        // 3,145,728
    const size_t WELEM = (size_t)E_ * E_;        // 147,456
    const size_t PEL   = (size_t)B_ * H_ * S_ * DP_;  // 4,194,304
    u16* ws = (u16*)d_ws;
    u16* xb  = ws;                                // NELEM (reused as AO)
    u16* wb  = xb + NELEM;                        // 4*WELEM
    u16* Qp  = wb + 4 * WELEM;                    // PEL
    u16* Kp  = Qp + PEL;                          // PEL
    u16* Vtp = Kp + PEL;                          // NELEM ([bh][48][2048])
    u16* AO  = xb;                                // alias: xb dead after gemm_qkv3

    dim3 blk(256);
    prep<<<dim3(3472), blk, 0, stream>>>(
        (const float4*)x, mask,
        (const float4*)Wq, (const float4*)Wk, (const float4*)Wv, (const float4*)Wo,
        (uint2*)xb, (uint2*)wb, Qp, Kp);

    gemm_qkv3<<<dim3(M_ / 64, 6), blk, 0, stream>>>(xb, wb, bq, bk, bv, Qp, Kp, Vtp);

    attn_mfma<<<dim3(B_ * H_, S_ / 128), blk, 0, stream>>>(Qp, Kp, Vtp, AO);

    gemm_out<<<dim3(M_ / 64, 6), blk, 0, stream>>>(AO, wb, bo, (float*)d_out);
}